// Round 6
// baseline (678.110 us; speedup 1.0000x reference)
//
#include <hip/hip_runtime.h>

#define B_ 128
#define S_ 48
#define P_ 60
#define I_ 512
#define H_ 512
#define NF_ 4
#define O_ 2

typedef __bf16 bf16x8 __attribute__((ext_vector_type(8)));
typedef float f32x4 __attribute__((ext_vector_type(4)));
typedef unsigned long long u64;

// ---------------- K_fused: emb producers (blocks 128-255) + GRU (blocks 0-127) ----
// R21: K1 fused into the cooperative kernel so the 755MB alpha/emb stream runs
// UNDER the GRU chain's latency shadow instead of serially before it.
//  - GRU role: R20 body verbatim (proven 578us / absmax 0.0078). Only deltas:
//    (1) blockDim 512 with waves 4-7 sync-matching idle; (2) eb loads become
//    agent-scope u64 pairs (same addresses/values — emb is now produced by
//    concurrent blocks, so plain cached loads could see stale L2); (3) a
//    column-ready gate before eb issue (register no-op after sentinel).
//  - emb role: K1's math per (batch,s) column, 2 batches/block/column.
//    64 blocks sweep s=0..23, 64 sweep s=47..24 => each GRU direction's next
//    column is produced ahead of consumption. Release = proven idiom:
//    agent u32 emb stores -> __syncthreads (vmcnt(0) drain) -> percol[s]++.
//    Last block of a half's last column sets the halfdone sentinel.
// Workspace layout unchanged (44.7MB). K4 unchanged.
__global__ __launch_bounds__(512, 2) void k_fused(
    const float* __restrict__ inputs, const float* __restrict__ conv_w,
    const float* __restrict__ conv_b,
    const float* __restrict__ whh_f, const float* __restrict__ whh_b,
    const float* __restrict__ wih_f, const float* __restrict__ wih_b,
    const float* __restrict__ bhh_f, const float* __restrict__ bhh_b,
    const float* __restrict__ bih_f, const float* __restrict__ bih_b,
    float* __restrict__ alpha_out,       // [B][S][P]
    unsigned* __restrict__ emb32,        // [B][S][256] u32 (bf16 pairs)
    u64* __restrict__ hbf,               // [S+1][2 dir][B][H/4] bf16x4-as-u64
    float* __restrict__ hs,              // [B][S][2H] fp32
    unsigned* __restrict__ bar,          // [S][4 grp][32 blk] x 16-u32 flags
    unsigned* __restrict__ percol)       // [48] col counters + [2] halfdone
{
  __shared__ __bf16 Ahh[48 * 512];
  __shared__ __bf16 Aih[48 * 512];
  __shared__ float part2[8][512];

  int bid = blockIdx.x;

  if (bid < 128) {
    // =================== GRU role (R20 protocol, proven) ===================
    int dir = bid >> 6;                    // 64 blocks per dir
    int j0  = (bid & 31) * 16;             // j-chunk of 16
    int m0  = ((bid >> 5) & 1) * 64;       // batch-half of 64
    int myi = bid & 31;                    // index within sync group
    int grp = bid >> 5;                    // group = (dir, batch-half), 0..3
    const float* Whh_d = dir ? whh_b : whh_f;
    const float* Wih_d = dir ? wih_b : wih_f;

    // weight slices in LDS (16B-granule XOR swizzle) — identical content to R20
    for (int it = threadIdx.x; it < 48 * 64; it += 512) {
      int r = it >> 6, c8 = it & 63;
      int grow = (r >> 4) * H_ + j0 + (r & 15);
      int dst = r * 512 + ((c8 ^ (r & 7)) * 8);
      const float* sh = Whh_d + (size_t)grow * I_ + c8 * 8;
      const float* si = Wih_d + (size_t)grow * I_ + c8 * 8;
      float4 a = *(const float4*)(sh), b = *(const float4*)(sh + 4);
      float4 c = *(const float4*)(si), d = *(const float4*)(si + 4);
      bf16x8 oh, oi;
      oh[0]=(__bf16)a.x; oh[1]=(__bf16)a.y; oh[2]=(__bf16)a.z; oh[3]=(__bf16)a.w;
      oh[4]=(__bf16)b.x; oh[5]=(__bf16)b.y; oh[6]=(__bf16)b.z; oh[7]=(__bf16)b.w;
      oi[0]=(__bf16)c.x; oi[1]=(__bf16)c.y; oi[2]=(__bf16)c.z; oi[3]=(__bf16)c.w;
      oi[4]=(__bf16)d.x; oi[5]=(__bf16)d.y; oi[6]=(__bf16)d.z; oi[7]=(__bf16)d.w;
      *(bf16x8*)(Ahh + dst) = oh;
      *(bf16x8*)(Aih + dst) = oi;
    }
    __syncthreads();

    if (threadIdx.x < 256) {
      // ---- active waves 0-3: R20 step loop ----
      int wave = threadIdx.x >> 6, lane = threadIdx.x & 63;
      int col = lane & 15, hi = lane >> 4;
      int b = m0 + wave * 16 + col;
      int j = j0 + hi * 4;
      const float* bhh = dir ? bhh_b : bhh_f;
      const float* bih = dir ? bih_b : bih_f;
      float4 bhr = *(const float4*)(bhh + j);
      float4 bhz = *(const float4*)(bhh + H_ + j);
      float4 bhn = *(const float4*)(bhh + 2 * H_ + j);
      float4 bxr = *(const float4*)(bih + j);
      float4 bxz = *(const float4*)(bih + H_ + j);
      float4 bxn = *(const float4*)(bih + 2 * H_ + j);
      float bhhA[3][4] = {{bhr.x,bhr.y,bhr.z,bhr.w},{bhz.x,bhz.y,bhz.z,bhz.w},{bhn.x,bhn.y,bhn.z,bhn.w}};
      float bihA[3][4] = {{bxr.x,bxr.y,bxr.z,bxr.w},{bxz.x,bxz.y,bxz.z,bxz.w},{bxn.x,bxn.y,bxn.z,bxn.w}};
      int rb0 = (0 * 16 + col) * 512, rb1 = (1 * 16 + col) * 512, rb2 = (2 * 16 + col) * 512;
      int csw = col & 7;
      const u64* embB64 = (const u64*)emb32 + (size_t)b * S_ * 128;

      const size_t STEPBUF = (size_t)2 * B_ * (H_ / 4);
      size_t hoff = ((size_t)dir * B_ + b) * (H_ / 4);
      const u64* hd64 = (const u64*)(percol + 48);

      float hprev[4] = {0.f, 0.f, 0.f, 0.f};
      int esent = 0;

      for (int step = 0; step < S_; ++step) {
        int t = dir ? (S_ - 1 - step) : step;

        // column-ready gate: register no-op once both halves are done.
        if (!esent) {
          u64 hd = __hip_atomic_load(hd64, __ATOMIC_RELAXED, __HIP_MEMORY_SCOPE_AGENT);
          if (hd == 0x0000000100000001ull) esent = 1;
          else while (__hip_atomic_load(percol + t, __ATOMIC_RELAXED,
                                        __HIP_MEMORY_SCOPE_AGENT) < 64u) {}
        }

        // emb loads (agent-scope; producers are concurrent blocks). Issued
        // BEFORE the h-flag poll so their latency overlaps the wait.
        const u64* erow64 = embB64 + (size_t)t * 128;
        u64 ebu[32];
        #pragma unroll
        for (int kk = 0; kk < 16; ++kk) {
          ebu[2 * kk]     = __hip_atomic_load(erow64 + kk * 8 + hi * 2,
                                              __ATOMIC_RELAXED, __HIP_MEMORY_SCOPE_AGENT);
          ebu[2 * kk + 1] = __hip_atomic_load(erow64 + kk * 8 + hi * 2 + 1,
                                              __ATOMIC_RELAXED, __HIP_MEMORY_SCOPE_AGENT);
        }

        if (step != 0) {
          if (threadIdx.x < 32) {
            const unsigned* pf = bar + (((unsigned)step * 4 + grp) * 32 + threadIdx.x) * 16;
            while (__hip_atomic_load(pf, __ATOMIC_RELAXED, __HIP_MEMORY_SCOPE_AGENT) == 0u) {}
          }
          __syncthreads();
        }

        const u64* hin = hbf + (size_t)step * STEPBUF + hoff;
        u64 hb[32];
        #pragma unroll
        for (int kk = 0; kk < 16; ++kk) {
          hb[2 * kk]     = __hip_atomic_load(hin + kk * 8 + hi * 2, __ATOMIC_RELAXED,
                                             __HIP_MEMORY_SCOPE_AGENT);
          hb[2 * kk + 1] = __hip_atomic_load(hin + kk * 8 + hi * 2 + 1, __ATOMIC_RELAXED,
                                             __HIP_MEMORY_SCOPE_AGENT);
        }

        f32x4 ah0 = {0,0,0,0}, ah1 = {0,0,0,0}, ah2 = {0,0,0,0};
        f32x4 ax0 = {0,0,0,0}, ax1 = {0,0,0,0}, ax2 = {0,0,0,0};
        #pragma unroll
        for (int kk = 0; kk < 16; ++kk) {
          union { u64 u[2]; bf16x8 v; } bu, eu;
          bu.u[0] = hb[2 * kk];
          bu.u[1] = hb[2 * kk + 1];
          eu.u[0] = ebu[2 * kk];
          eu.u[1] = ebu[2 * kk + 1];
          int go = ((kk * 4 + hi) ^ csw) * 8;
          bf16x8 a0 = *(const bf16x8*)(Ahh + rb0 + go);
          bf16x8 a1 = *(const bf16x8*)(Ahh + rb1 + go);
          bf16x8 a2 = *(const bf16x8*)(Ahh + rb2 + go);
          bf16x8 w0 = *(const bf16x8*)(Aih + rb0 + go);
          bf16x8 w1 = *(const bf16x8*)(Aih + rb1 + go);
          bf16x8 w2 = *(const bf16x8*)(Aih + rb2 + go);
          ah0 = __builtin_amdgcn_mfma_f32_16x16x32_bf16(a0, bu.v, ah0, 0, 0, 0);
          ax0 = __builtin_amdgcn_mfma_f32_16x16x32_bf16(w0, eu.v, ax0, 0, 0, 0);
          ah1 = __builtin_amdgcn_mfma_f32_16x16x32_bf16(a1, bu.v, ah1, 0, 0, 0);
          ax1 = __builtin_amdgcn_mfma_f32_16x16x32_bf16(w1, eu.v, ax1, 0, 0, 0);
          ah2 = __builtin_amdgcn_mfma_f32_16x16x32_bf16(a2, bu.v, ah2, 0, 0, 0);
          ax2 = __builtin_amdgcn_mfma_f32_16x16x32_bf16(w2, eu.v, ax2, 0, 0, 0);
        }

        union { u64 u; __bf16 h[4]; } pk;
        #pragma unroll
        for (int r = 0; r < 4; r++) {
          float hr = ah0[r] + bhhA[0][r];
          float hz = ah1[r] + bhhA[1][r];
          float hn = ah2[r] + bhhA[2][r];
          float xr = ax0[r] + bihA[0][r];
          float xz = ax1[r] + bihA[1][r];
          float xn = ax2[r] + bihA[2][r];
          float rg = 1.f / (1.f + __expf(-(xr + hr)));
          float zg = 1.f / (1.f + __expf(-(xz + hz)));
          float ng = tanhf(xn + rg * hn);
          float hnew = (1.f - zg) * ng + zg * hprev[r];
          hprev[r] = hnew;
          pk.h[r] = (__bf16)hnew;
        }

        if (step != S_ - 1) {
          u64* hout = hbf + (size_t)(step + 1) * STEPBUF + hoff;
          __hip_atomic_store(hout + (j0 >> 2) + hi, pk.u, __ATOMIC_RELAXED,
                             __HIP_MEMORY_SCOPE_AGENT);
          // release: __syncthreads drains vmcnt(0) -> h-store acked, then flag.
          __syncthreads();
          if (threadIdx.x == 0)
            __hip_atomic_store(bar + (((unsigned)(step + 1) * 4 + grp) * 32 + myi) * 16,
                               1u, __ATOMIC_RELAXED, __HIP_MEMORY_SCOPE_AGENT);
        }

        float4 hv = {hprev[0], hprev[1], hprev[2], hprev[3]};
        *(float4*)(hs + ((size_t)b * S_ + t) * (2 * H_) + dir * H_ + j) = hv;
      }
    } else {
      // ---- idle waves 4-7: match the active loop's __syncthreads count ----
      for (int step = 0; step < S_; ++step) {
        if (step != 0) __syncthreads();
        if (step != S_ - 1) __syncthreads();
      }
    }
  } else {
    // =================== emb role (K1's math, column-ordered) ==============
    int bid2 = bid - 128;
    int half = bid2 >> 6;                 // 0: s=0..23, 1: s=47..24
    int blk  = bid2 & 63;
    int bA   = blk * 2;
    int wv   = threadIdx.x >> 6, lane = threadIdx.x & 63;
    int batch = bA + (wv >> 2);           // waves 0-3 -> bA, waves 4-7 -> bA+1
    int wsub  = wv & 3;

    float w[8];
    {
      const float4* c4 = (const float4*)(conv_w + lane * 8);
      float4 a = c4[0], bq = c4[1];
      w[0]=a.x; w[1]=a.y; w[2]=a.z; w[3]=a.w; w[4]=bq.x; w[5]=bq.y; w[6]=bq.z; w[7]=bq.w;
    }
    float cb0 = conv_b[0];

    for (int c = 0; c < 24; ++c) {
      int s = half ? (47 - c) : c;
      const float* xb = inputs + ((size_t)batch * S_ + s) * (P_ * I_);

      float acc[8] = {0,0,0,0,0,0,0,0};
      for (int p = wsub; p < P_; p += 4) {
        const float4* xr = (const float4*)(xb + (size_t)p * I_ + lane * 8);
        float4 a = xr[0], bq = xr[1];
        float xv[8] = {a.x,a.y,a.z,a.w,bq.x,bq.y,bq.z,bq.w};
        float d = 0.f;
        #pragma unroll
        for (int jj = 0; jj < 8; jj++) d += xv[jj] * w[jj];
        #pragma unroll
        for (int off = 32; off >= 1; off >>= 1) d += __shfl_xor(d, off);
        float al = fminf(fmaxf(d + cb0, 0.f), 1.f);
        if (lane == 0) alpha_out[((size_t)batch * S_ + s) * P_ + p] = al;
        #pragma unroll
        for (int jj = 0; jj < 8; jj++) acc[jj] += al * xv[jj];
      }
      #pragma unroll
      for (int jj = 0; jj < 8; jj++) part2[wv][lane * 8 + jj] = acc[jj];
      __syncthreads();

      {
        int tid = threadIdx.x;
        int bsel = tid >> 8;              // 0 -> bA, 1 -> bA+1
        int wbase = bsel * 4;
        int widx = tid & 255;
        int jb = widx * 2;
        float s0 = part2[wbase][jb]   + part2[wbase+1][jb]
                 + part2[wbase+2][jb] + part2[wbase+3][jb];
        float s1 = part2[wbase][jb+1]   + part2[wbase+1][jb+1]
                 + part2[wbase+2][jb+1] + part2[wbase+3][jb+1];
        union { __bf16 h[2]; unsigned u; } up;
        up.h[0] = (__bf16)s0; up.h[1] = (__bf16)s1;
        int bout = bA + bsel;
        __hip_atomic_store(emb32 + ((size_t)bout * S_ + s) * 256 + widx, up.u,
                           __ATOMIC_RELAXED, __HIP_MEMORY_SCOPE_AGENT);
      }
      // release: drains vmcnt(0) -> emb stores acked at the coherence point;
      // also guards part2 reuse next column.
      __syncthreads();
      if (threadIdx.x == 0) {
        unsigned old = __hip_atomic_fetch_add(percol + s, 1u, __ATOMIC_RELAXED,
                                              __HIP_MEMORY_SCOPE_AGENT);
        if (old == 63u && c == 23)
          __hip_atomic_store(percol + 48 + half, 1u, __ATOMIC_RELAXED,
                             __HIP_MEMORY_SCOPE_AGENT);
      }
    }
  }
}

// ---------------- K4: beta attention + final linear + softmax ----------------
__global__ __launch_bounds__(256) void k_attn(
    const float* __restrict__ hs, const float* __restrict__ c2w,
    const float* __restrict__ c2b, const float* __restrict__ lin_w,
    const float* __restrict__ lin_b, float* __restrict__ out,
    float* __restrict__ beta_out)
{
  int b = blockIdx.x, tid = threadIdx.x;
  const float* st = hs + (size_t)b * S_ * (2 * H_);
  __shared__ float lg[NF_][S_];
  __shared__ float betas[NF_][S_];
  __shared__ float ctx[NF_ * 2 * H_];
  __shared__ float red[2][4];

  if (tid < NF_ * S_) {
    int f = tid / S_, s = tid - f * S_;
    const float4* sv = (const float4*)(st + (size_t)s * (2 * H_));
    const float4* wv = (const float4*)(c2w + (size_t)f * (2 * H_));
    float a = 0.f;
    for (int k = 0; k < 256; k++) {
      float4 x = sv[k], y = wv[k];
      a += x.x * y.x + x.y * y.y + x.z * y.z + x.w * y.w;
    }
    lg[f][s] = a + c2b[f];
  }
  __syncthreads();

  int wv_ = tid >> 6, ln = tid & 63;
  {
    float v = (ln < S_) ? lg[wv_][ln] : -3.4e38f;
    float m = v;
    #pragma unroll
    for (int off = 32; off >= 1; off >>= 1) m = fmaxf(m, __shfl_xor(m, off));
    float e = (ln < S_) ? __expf(v - m) : 0.f;
    float ssum = e;
    #pragma unroll
    for (int off = 32; off >= 1; off >>= 1) ssum += __shfl_xor(ssum, off);
    if (ln < S_) {
      float bta = e / ssum;
      betas[wv_][ln] = bta;
      beta_out[((size_t)b * NF_ + wv_) * S_ + ln] = bta;
    }
  }
  __syncthreads();

  for (int idx = tid; idx < NF_ * 2 * H_; idx += 256) {
    int f = idx >> 10, h = idx & 1023;
    float a = 0.f;
    for (int s = 0; s < S_; s++) a += betas[f][s] * st[(size_t)s * (2 * H_) + h];
    ctx[idx] = a;
  }
  __syncthreads();

  float p0 = 0.f, p1 = 0.f;
  for (int idx = tid; idx < NF_ * 2 * H_; idx += 256) {
    float c = ctx[idx];
    p0 += c * lin_w[idx];
    p1 += c * lin_w[NF_ * 2 * H_ + idx];
  }
  #pragma unroll
  for (int off = 32; off >= 1; off >>= 1) {
    p0 += __shfl_xor(p0, off);
    p1 += __shfl_xor(p1, off);
  }
  if (ln == 0) { red[0][wv_] = p0; red[1][wv_] = p1; }
  __syncthreads();
  if (tid == 0) {
    float l0 = red[0][0] + red[0][1] + red[0][2] + red[0][3] + lin_b[0];
    float l1 = red[1][0] + red[1][1] + red[1][2] + red[1][3] + lin_b[1];
    float m = fmaxf(l0, l1);
    float e0 = __expf(l0 - m), e1 = __expf(l1 - m);
    float s = e0 + e1;
    out[(size_t)b * O_ + 0] = e0 / s;
    out[(size_t)b * O_ + 1] = e1 / s;
  }
}

// ---------------- launch ----------------
extern "C" void kernel_launch(void* const* d_in, const int* in_sizes, int n_in,
                              void* d_out, int out_size, void* d_ws, size_t ws_size,
                              hipStream_t stream) {
  const float* inputs = (const float*)d_in[0];
  const float* conv_w = (const float*)d_in[1];
  const float* conv_b = (const float*)d_in[2];
  const float* wih_f  = (const float*)d_in[3];
  const float* whh_f  = (const float*)d_in[4];
  const float* bih_f  = (const float*)d_in[5];
  const float* bhh_f  = (const float*)d_in[6];
  const float* wih_b  = (const float*)d_in[7];
  const float* whh_b  = (const float*)d_in[8];
  const float* bih_b  = (const float*)d_in[9];
  const float* bhh_b  = (const float*)d_in[10];
  const float* c2w    = (const float*)d_in[11];
  const float* c2b    = (const float*)d_in[12];
  const float* lin_w  = (const float*)d_in[13];
  const float* lin_b  = (const float*)d_in[14];

  float* out   = (float*)d_out;
  float* alpha = out + B_ * O_;                       // [B,S,P]
  float* beta  = alpha + (size_t)B_ * S_ * P_;        // [B,NF,S]

  char* ws = (char*)d_ws;
  unsigned* emb32 = (unsigned*)ws;                    // 6,291,456 B  [B][S][256] u32
  float*  hs      = (float*)(ws + 6291456);           // 25,165,824 B [B][S][2H]
  unsigned* bar   = (unsigned*)(ws + 31457280);       // 393,216 B    [S][4][32]x16-u32 flags
  unsigned* percol= (unsigned*)(ws + 31850496);       // 200 B        [48]+[2] counters
  u64*    hbf     = (u64*)(ws + 31858688);            // 12,845,056 B [S+1][2][B][H/4]

  // zero flags + percol/halfdone + step-0 h buffer (contiguous region)
  hipMemsetAsync((void*)bar, 0, 401408 + 262144, stream);

  {
    float* alpha_arg = alpha;
    void* args[] = {(void*)&inputs, (void*)&conv_w, (void*)&conv_b,
                    (void*)&whh_f, (void*)&whh_b, (void*)&wih_f, (void*)&wih_b,
                    (void*)&bhh_f, (void*)&bhh_b, (void*)&bih_f, (void*)&bih_b,
                    (void*)&alpha_arg, (void*)&emb32, (void*)&hbf, (void*)&hs,
                    (void*)&bar, (void*)&percol};
    hipLaunchCooperativeKernel((void*)k_fused, dim3(256), dim3(512), args, 0, stream);
  }

  k_attn<<<B_, 256, 0, stream>>>(hs, c2w, c2b, lin_w, lin_b, out, beta);
}

// Round 7
// 574.349 us; speedup vs baseline: 1.1807x; 1.1807x over previous
//
#include <hip/hip_runtime.h>

#define B_ 128
#define S_ 48
#define P_ 60
#define I_ 512
#define H_ 512
#define NF_ 4
#define O_ 2

typedef __bf16 bf16x8 __attribute__((ext_vector_type(8)));
typedef float f32x4 __attribute__((ext_vector_type(4)));
typedef unsigned long long u64;

// ---------------- K_fused: emb producers (blocks 128-255) + GRU (blocks 0-127) ----
// R22: R21 structure/sync VERBATIM (passed, absmax 0.0078). Only the producer
// inner p-loop is rewritten for ILP: unroll x5 (15 iters = 3x5), 10 float4
// loads issued up front (10KB/wave in flight), 5 independent interleaved
// shfl-reduce chains. Per-wave partials BIT-IDENTICAL to R21 (same p sequence
// wsub+4i ascending, same accumulation order, same shfl offsets). R21's
// measured producer was 26us/col = 6.5 GB/s/CU (2 loads + serial shfl chain,
// latency-bound at 19% occupancy) and starved the GRU gate; this targets
// ~10-13us/col.
__global__ __launch_bounds__(512, 2) void k_fused(
    const float* __restrict__ inputs, const float* __restrict__ conv_w,
    const float* __restrict__ conv_b,
    const float* __restrict__ whh_f, const float* __restrict__ whh_b,
    const float* __restrict__ wih_f, const float* __restrict__ wih_b,
    const float* __restrict__ bhh_f, const float* __restrict__ bhh_b,
    const float* __restrict__ bih_f, const float* __restrict__ bih_b,
    float* __restrict__ alpha_out,       // [B][S][P]
    unsigned* __restrict__ emb32,        // [B][S][256] u32 (bf16 pairs)
    u64* __restrict__ hbf,               // [S+1][2 dir][B][H/4] bf16x4-as-u64
    float* __restrict__ hs,              // [B][S][2H] fp32
    unsigned* __restrict__ bar,          // [S][4 grp][32 blk] x 16-u32 flags
    unsigned* __restrict__ percol)       // [48] col counters + [2] halfdone
{
  __shared__ __bf16 Ahh[48 * 512];
  __shared__ __bf16 Aih[48 * 512];
  __shared__ float part2[8][512];

  int bid = blockIdx.x;

  if (bid < 128) {
    // =================== GRU role (R20 protocol, proven) ===================
    int dir = bid >> 6;                    // 64 blocks per dir
    int j0  = (bid & 31) * 16;             // j-chunk of 16
    int m0  = ((bid >> 5) & 1) * 64;       // batch-half of 64
    int myi = bid & 31;                    // index within sync group
    int grp = bid >> 5;                    // group = (dir, batch-half), 0..3
    const float* Whh_d = dir ? whh_b : whh_f;
    const float* Wih_d = dir ? wih_b : wih_f;

    // weight slices in LDS (16B-granule XOR swizzle) — identical content to R20
    for (int it = threadIdx.x; it < 48 * 64; it += 512) {
      int r = it >> 6, c8 = it & 63;
      int grow = (r >> 4) * H_ + j0 + (r & 15);
      int dst = r * 512 + ((c8 ^ (r & 7)) * 8);
      const float* sh = Whh_d + (size_t)grow * I_ + c8 * 8;
      const float* si = Wih_d + (size_t)grow * I_ + c8 * 8;
      float4 a = *(const float4*)(sh), b = *(const float4*)(sh + 4);
      float4 c = *(const float4*)(si), d = *(const float4*)(si + 4);
      bf16x8 oh, oi;
      oh[0]=(__bf16)a.x; oh[1]=(__bf16)a.y; oh[2]=(__bf16)a.z; oh[3]=(__bf16)a.w;
      oh[4]=(__bf16)b.x; oh[5]=(__bf16)b.y; oh[6]=(__bf16)b.z; oh[7]=(__bf16)b.w;
      oi[0]=(__bf16)c.x; oi[1]=(__bf16)c.y; oi[2]=(__bf16)c.z; oi[3]=(__bf16)c.w;
      oi[4]=(__bf16)d.x; oi[5]=(__bf16)d.y; oi[6]=(__bf16)d.z; oi[7]=(__bf16)d.w;
      *(bf16x8*)(Ahh + dst) = oh;
      *(bf16x8*)(Aih + dst) = oi;
    }
    __syncthreads();

    if (threadIdx.x < 256) {
      // ---- active waves 0-3: R20 step loop ----
      int wave = threadIdx.x >> 6, lane = threadIdx.x & 63;
      int col = lane & 15, hi = lane >> 4;
      int b = m0 + wave * 16 + col;
      int j = j0 + hi * 4;
      const float* bhh = dir ? bhh_b : bhh_f;
      const float* bih = dir ? bih_b : bih_f;
      float4 bhr = *(const float4*)(bhh + j);
      float4 bhz = *(const float4*)(bhh + H_ + j);
      float4 bhn = *(const float4*)(bhh + 2 * H_ + j);
      float4 bxr = *(const float4*)(bih + j);
      float4 bxz = *(const float4*)(bih + H_ + j);
      float4 bxn = *(const float4*)(bih + 2 * H_ + j);
      float bhhA[3][4] = {{bhr.x,bhr.y,bhr.z,bhr.w},{bhz.x,bhz.y,bhz.z,bhz.w},{bhn.x,bhn.y,bhn.z,bhn.w}};
      float bihA[3][4] = {{bxr.x,bxr.y,bxr.z,bxr.w},{bxz.x,bxz.y,bxz.z,bxz.w},{bxn.x,bxn.y,bxn.z,bxn.w}};
      int rb0 = (0 * 16 + col) * 512, rb1 = (1 * 16 + col) * 512, rb2 = (2 * 16 + col) * 512;
      int csw = col & 7;
      const u64* embB64 = (const u64*)emb32 + (size_t)b * S_ * 128;

      const size_t STEPBUF = (size_t)2 * B_ * (H_ / 4);
      size_t hoff = ((size_t)dir * B_ + b) * (H_ / 4);
      const u64* hd64 = (const u64*)(percol + 48);

      float hprev[4] = {0.f, 0.f, 0.f, 0.f};
      int esent = 0;

      for (int step = 0; step < S_; ++step) {
        int t = dir ? (S_ - 1 - step) : step;

        // column-ready gate: register no-op once both halves are done.
        if (!esent) {
          u64 hd = __hip_atomic_load(hd64, __ATOMIC_RELAXED, __HIP_MEMORY_SCOPE_AGENT);
          if (hd == 0x0000000100000001ull) esent = 1;
          else while (__hip_atomic_load(percol + t, __ATOMIC_RELAXED,
                                        __HIP_MEMORY_SCOPE_AGENT) < 64u) {}
        }

        // emb loads (agent-scope; producers are concurrent blocks). Issued
        // BEFORE the h-flag poll so their latency overlaps the wait.
        const u64* erow64 = embB64 + (size_t)t * 128;
        u64 ebu[32];
        #pragma unroll
        for (int kk = 0; kk < 16; ++kk) {
          ebu[2 * kk]     = __hip_atomic_load(erow64 + kk * 8 + hi * 2,
                                              __ATOMIC_RELAXED, __HIP_MEMORY_SCOPE_AGENT);
          ebu[2 * kk + 1] = __hip_atomic_load(erow64 + kk * 8 + hi * 2 + 1,
                                              __ATOMIC_RELAXED, __HIP_MEMORY_SCOPE_AGENT);
        }

        if (step != 0) {
          if (threadIdx.x < 32) {
            const unsigned* pf = bar + (((unsigned)step * 4 + grp) * 32 + threadIdx.x) * 16;
            while (__hip_atomic_load(pf, __ATOMIC_RELAXED, __HIP_MEMORY_SCOPE_AGENT) == 0u) {}
          }
          __syncthreads();
        }

        const u64* hin = hbf + (size_t)step * STEPBUF + hoff;
        u64 hb[32];
        #pragma unroll
        for (int kk = 0; kk < 16; ++kk) {
          hb[2 * kk]     = __hip_atomic_load(hin + kk * 8 + hi * 2, __ATOMIC_RELAXED,
                                             __HIP_MEMORY_SCOPE_AGENT);
          hb[2 * kk + 1] = __hip_atomic_load(hin + kk * 8 + hi * 2 + 1, __ATOMIC_RELAXED,
                                             __HIP_MEMORY_SCOPE_AGENT);
        }

        f32x4 ah0 = {0,0,0,0}, ah1 = {0,0,0,0}, ah2 = {0,0,0,0};
        f32x4 ax0 = {0,0,0,0}, ax1 = {0,0,0,0}, ax2 = {0,0,0,0};
        #pragma unroll
        for (int kk = 0; kk < 16; ++kk) {
          union { u64 u[2]; bf16x8 v; } bu, eu;
          bu.u[0] = hb[2 * kk];
          bu.u[1] = hb[2 * kk + 1];
          eu.u[0] = ebu[2 * kk];
          eu.u[1] = ebu[2 * kk + 1];
          int go = ((kk * 4 + hi) ^ csw) * 8;
          bf16x8 a0 = *(const bf16x8*)(Ahh + rb0 + go);
          bf16x8 a1 = *(const bf16x8*)(Ahh + rb1 + go);
          bf16x8 a2 = *(const bf16x8*)(Ahh + rb2 + go);
          bf16x8 w0 = *(const bf16x8*)(Aih + rb0 + go);
          bf16x8 w1 = *(const bf16x8*)(Aih + rb1 + go);
          bf16x8 w2 = *(const bf16x8*)(Aih + rb2 + go);
          ah0 = __builtin_amdgcn_mfma_f32_16x16x32_bf16(a0, bu.v, ah0, 0, 0, 0);
          ax0 = __builtin_amdgcn_mfma_f32_16x16x32_bf16(w0, eu.v, ax0, 0, 0, 0);
          ah1 = __builtin_amdgcn_mfma_f32_16x16x32_bf16(a1, bu.v, ah1, 0, 0, 0);
          ax1 = __builtin_amdgcn_mfma_f32_16x16x32_bf16(w1, eu.v, ax1, 0, 0, 0);
          ah2 = __builtin_amdgcn_mfma_f32_16x16x32_bf16(a2, bu.v, ah2, 0, 0, 0);
          ax2 = __builtin_amdgcn_mfma_f32_16x16x32_bf16(w2, eu.v, ax2, 0, 0, 0);
        }

        union { u64 u; __bf16 h[4]; } pk;
        #pragma unroll
        for (int r = 0; r < 4; r++) {
          float hr = ah0[r] + bhhA[0][r];
          float hz = ah1[r] + bhhA[1][r];
          float hn = ah2[r] + bhhA[2][r];
          float xr = ax0[r] + bihA[0][r];
          float xz = ax1[r] + bihA[1][r];
          float xn = ax2[r] + bihA[2][r];
          float rg = 1.f / (1.f + __expf(-(xr + hr)));
          float zg = 1.f / (1.f + __expf(-(xz + hz)));
          float ng = tanhf(xn + rg * hn);
          float hnew = (1.f - zg) * ng + zg * hprev[r];
          hprev[r] = hnew;
          pk.h[r] = (__bf16)hnew;
        }

        if (step != S_ - 1) {
          u64* hout = hbf + (size_t)(step + 1) * STEPBUF + hoff;
          __hip_atomic_store(hout + (j0 >> 2) + hi, pk.u, __ATOMIC_RELAXED,
                             __HIP_MEMORY_SCOPE_AGENT);
          // release: __syncthreads drains vmcnt(0) -> h-store acked, then flag.
          __syncthreads();
          if (threadIdx.x == 0)
            __hip_atomic_store(bar + (((unsigned)(step + 1) * 4 + grp) * 32 + myi) * 16,
                               1u, __ATOMIC_RELAXED, __HIP_MEMORY_SCOPE_AGENT);
        }

        float4 hv = {hprev[0], hprev[1], hprev[2], hprev[3]};
        *(float4*)(hs + ((size_t)b * S_ + t) * (2 * H_) + dir * H_ + j) = hv;
      }
    } else {
      // ---- idle waves 4-7: match the active loop's __syncthreads count ----
      for (int step = 0; step < S_; ++step) {
        if (step != 0) __syncthreads();
        if (step != S_ - 1) __syncthreads();
      }
    }
  } else {
    // =================== emb role (K1's math, column-ordered) ==============
    int bid2 = bid - 128;
    int half = bid2 >> 6;                 // 0: s=0..23, 1: s=47..24
    int blk  = bid2 & 63;
    int bA   = blk * 2;
    int wv   = threadIdx.x >> 6, lane = threadIdx.x & 63;
    int batch = bA + (wv >> 2);           // waves 0-3 -> bA, waves 4-7 -> bA+1
    int wsub  = wv & 3;

    float w[8];
    {
      const float4* c4 = (const float4*)(conv_w + lane * 8);
      float4 a = c4[0], bq = c4[1];
      w[0]=a.x; w[1]=a.y; w[2]=a.z; w[3]=a.w; w[4]=bq.x; w[5]=bq.y; w[6]=bq.z; w[7]=bq.w;
    }
    float cb0 = conv_b[0];

    for (int c = 0; c < 24; ++c) {
      int s = half ? (47 - c) : c;
      const float* xb = inputs + ((size_t)batch * S_ + s) * (P_ * I_);

      float acc[8] = {0,0,0,0,0,0,0,0};
      // p-loop, unroll x5 (p = wsub + 4i, i ascending; 15 iters = 3 groups of 5).
      // 10 float4 loads issued up front per group; 5 independent shfl chains
      // interleaved. Per-wave partial is BIT-IDENTICAL to R21 (same p order,
      // same accumulation order, same shfl offsets).
      for (int g = 0; g < 3; ++g) {
        int pbase = wsub + g * 20;
        float xv[5][8];
        float d[5];
        #pragma unroll
        for (int u = 0; u < 5; ++u) {
          const float4* xr = (const float4*)(xb + (size_t)(pbase + 4 * u) * I_ + lane * 8);
          float4 a = xr[0], bq = xr[1];
          xv[u][0]=a.x; xv[u][1]=a.y; xv[u][2]=a.z; xv[u][3]=a.w;
          xv[u][4]=bq.x; xv[u][5]=bq.y; xv[u][6]=bq.z; xv[u][7]=bq.w;
        }
        #pragma unroll
        for (int u = 0; u < 5; ++u) {
          float dd = 0.f;
          #pragma unroll
          for (int jj = 0; jj < 8; jj++) dd += xv[u][jj] * w[jj];
          d[u] = dd;
        }
        #pragma unroll
        for (int off = 32; off >= 1; off >>= 1) {
          #pragma unroll
          for (int u = 0; u < 5; ++u) d[u] += __shfl_xor(d[u], off);
        }
        #pragma unroll
        for (int u = 0; u < 5; ++u) {
          float al = fminf(fmaxf(d[u] + cb0, 0.f), 1.f);
          if (lane == 0) alpha_out[((size_t)batch * S_ + s) * P_ + pbase + 4 * u] = al;
          #pragma unroll
          for (int jj = 0; jj < 8; jj++) acc[jj] += al * xv[u][jj];
        }
      }
      #pragma unroll
      for (int jj = 0; jj < 8; jj++) part2[wv][lane * 8 + jj] = acc[jj];
      __syncthreads();

      {
        int tid = threadIdx.x;
        int bsel = tid >> 8;              // 0 -> bA, 1 -> bA+1
        int wbase = bsel * 4;
        int widx = tid & 255;
        int jb = widx * 2;
        float s0 = part2[wbase][jb]   + part2[wbase+1][jb]
                 + part2[wbase+2][jb] + part2[wbase+3][jb];
        float s1 = part2[wbase][jb+1]   + part2[wbase+1][jb+1]
                 + part2[wbase+2][jb+1] + part2[wbase+3][jb+1];
        union { __bf16 h[2]; unsigned u; } up;
        up.h[0] = (__bf16)s0; up.h[1] = (__bf16)s1;
        int bout = bA + bsel;
        __hip_atomic_store(emb32 + ((size_t)bout * S_ + s) * 256 + widx, up.u,
                           __ATOMIC_RELAXED, __HIP_MEMORY_SCOPE_AGENT);
      }
      // release: drains vmcnt(0) -> emb stores acked at the coherence point;
      // also guards part2 reuse next column.
      __syncthreads();
      if (threadIdx.x == 0) {
        unsigned old = __hip_atomic_fetch_add(percol + s, 1u, __ATOMIC_RELAXED,
                                              __HIP_MEMORY_SCOPE_AGENT);
        if (old == 63u && c == 23)
          __hip_atomic_store(percol + 48 + half, 1u, __ATOMIC_RELAXED,
                             __HIP_MEMORY_SCOPE_AGENT);
      }
    }
  }
}

// ---------------- K4: beta attention + final linear + softmax ----------------
__global__ __launch_bounds__(256) void k_attn(
    const float* __restrict__ hs, const float* __restrict__ c2w,
    const float* __restrict__ c2b, const float* __restrict__ lin_w,
    const float* __restrict__ lin_b, float* __restrict__ out,
    float* __restrict__ beta_out)
{
  int b = blockIdx.x, tid = threadIdx.x;
  const float* st = hs + (size_t)b * S_ * (2 * H_);
  __shared__ float lg[NF_][S_];
  __shared__ float betas[NF_][S_];
  __shared__ float ctx[NF_ * 2 * H_];
  __shared__ float red[2][4];

  if (tid < NF_ * S_) {
    int f = tid / S_, s = tid - f * S_;
    const float4* sv = (const float4*)(st + (size_t)s * (2 * H_));
    const float4* wv = (const float4*)(c2w + (size_t)f * (2 * H_));
    float a = 0.f;
    for (int k = 0; k < 256; k++) {
      float4 x = sv[k], y = wv[k];
      a += x.x * y.x + x.y * y.y + x.z * y.z + x.w * y.w;
    }
    lg[f][s] = a + c2b[f];
  }
  __syncthreads();

  int wv_ = tid >> 6, ln = tid & 63;
  {
    float v = (ln < S_) ? lg[wv_][ln] : -3.4e38f;
    float m = v;
    #pragma unroll
    for (int off = 32; off >= 1; off >>= 1) m = fmaxf(m, __shfl_xor(m, off));
    float e = (ln < S_) ? __expf(v - m) : 0.f;
    float ssum = e;
    #pragma unroll
    for (int off = 32; off >= 1; off >>= 1) ssum += __shfl_xor(ssum, off);
    if (ln < S_) {
      float bta = e / ssum;
      betas[wv_][ln] = bta;
      beta_out[((size_t)b * NF_ + wv_) * S_ + ln] = bta;
    }
  }
  __syncthreads();

  for (int idx = tid; idx < NF_ * 2 * H_; idx += 256) {
    int f = idx >> 10, h = idx & 1023;
    float a = 0.f;
    for (int s = 0; s < S_; s++) a += betas[f][s] * st[(size_t)s * (2 * H_) + h];
    ctx[idx] = a;
  }
  __syncthreads();

  float p0 = 0.f, p1 = 0.f;
  for (int idx = tid; idx < NF_ * 2 * H_; idx += 256) {
    float c = ctx[idx];
    p0 += c * lin_w[idx];
    p1 += c * lin_w[NF_ * 2 * H_ + idx];
  }
  #pragma unroll
  for (int off = 32; off >= 1; off >>= 1) {
    p0 += __shfl_xor(p0, off);
    p1 += __shfl_xor(p1, off);
  }
  if (ln == 0) { red[0][wv_] = p0; red[1][wv_] = p1; }
  __syncthreads();
  if (tid == 0) {
    float l0 = red[0][0] + red[0][1] + red[0][2] + red[0][3] + lin_b[0];
    float l1 = red[1][0] + red[1][1] + red[1][2] + red[1][3] + lin_b[1];
    float m = fmaxf(l0, l1);
    float e0 = __expf(l0 - m), e1 = __expf(l1 - m);
    float s = e0 + e1;
    out[(size_t)b * O_ + 0] = e0 / s;
    out[(size_t)b * O_ + 1] = e1 / s;
  }
}

// ---------------- launch ----------------
extern "C" void kernel_launch(void* const* d_in, const int* in_sizes, int n_in,
                              void* d_out, int out_size, void* d_ws, size_t ws_size,
                              hipStream_t stream) {
  const float* inputs = (const float*)d_in[0];
  const float* conv_w = (const float*)d_in[1];
  const float* conv_b = (const float*)d_in[2];
  const float* wih_f  = (const float*)d_in[3];
  const float* whh_f  = (const float*)d_in[4];
  const float* bih_f  = (const float*)d_in[5];
  const float* bhh_f  = (const float*)d_in[6];
  const float* wih_b  = (const float*)d_in[7];
  const float* whh_b  = (const float*)d_in[8];
  const float* bih_b  = (const float*)d_in[9];
  const float* bhh_b  = (const float*)d_in[10];
  const float* c2w    = (const float*)d_in[11];
  const float* c2b    = (const float*)d_in[12];
  const float* lin_w  = (const float*)d_in[13];
  const float* lin_b  = (const float*)d_in[14];

  float* out   = (float*)d_out;
  float* alpha = out + B_ * O_;                       // [B,S,P]
  float* beta  = alpha + (size_t)B_ * S_ * P_;        // [B,NF,S]

  char* ws = (char*)d_ws;
  unsigned* emb32 = (unsigned*)ws;                    // 6,291,456 B  [B][S][256] u32
  float*  hs      = (float*)(ws + 6291456);           // 25,165,824 B [B][S][2H]
  unsigned* bar   = (unsigned*)(ws + 31457280);       // 393,216 B    [S][4][32]x16-u32 flags
  unsigned* percol= (unsigned*)(ws + 31850496);       // 200 B        [48]+[2] counters
  u64*    hbf     = (u64*)(ws + 31858688);            // 12,845,056 B [S+1][2][B][H/4]

  // zero flags + percol/halfdone + step-0 h buffer (contiguous region)
  hipMemsetAsync((void*)bar, 0, 401408 + 262144, stream);

  {
    float* alpha_arg = alpha;
    void* args[] = {(void*)&inputs, (void*)&conv_w, (void*)&conv_b,
                    (void*)&whh_f, (void*)&whh_b, (void*)&wih_f, (void*)&wih_b,
                    (void*)&bhh_f, (void*)&bhh_b, (void*)&bih_f, (void*)&bih_b,
                    (void*)&alpha_arg, (void*)&emb32, (void*)&hbf, (void*)&hs,
                    (void*)&bar, (void*)&percol};
    hipLaunchCooperativeKernel((void*)k_fused, dim3(256), dim3(512), args, 0, stream);
  }

  k_attn<<<B_, 256, 0, stream>>>(hs, c2w, c2b, lin_w, lin_b, out, beta);
}